// Round 21
// baseline (81.424 us; speedup 1.0000x reference)
//
#include <hip/hip_runtime.h>

#define NV 1448
#define JD 4344     // 3*NV
#define CC 256
#define BB 64
#define QQ 128      // 2*BB
#define NP 1536     // 48 tiles of 32 (pads carry |p|^2 = 60000)
#define PADV 60000.0f

typedef __bf16    bf16x8 __attribute__((ext_vector_type(8)));
typedef _Float16  f16x8  __attribute__((ext_vector_type(8)));
typedef float     f32x4  __attribute__((ext_vector_type(4)));
typedef float     f32x16 __attribute__((ext_vector_type(16)));

__device__ __forceinline__ unsigned f2bf(float f) {
    unsigned u = __float_as_uint(f);
    return (u + 0x7FFFu + ((u >> 16) & 1u)) >> 16;
}
union HU { _Float16 h; unsigned short u; };
__device__ __forceinline__ unsigned short f2h(float f) { HU t; t.h = (_Float16)f; return t.u; }
__device__ __forceinline__ float h2f(unsigned short u) { HU t; t.u = u; return (float)t.h; }

#define MIN3A(dst, a, b) asm("v_min3_f32 %0, %0, %1, %2" : "+v"(dst) : "v"(a), "v"(b))

// ---------------------------------------------------------------------------
// K1: global average pool -> latQb[q][c] (bf16). Thread 0 zeroes acc.
// ---------------------------------------------------------------------------
__global__ __launch_bounds__(256) void pool_kernel(const float* __restrict__ inp,
                                                   const float* __restrict__ tgt,
                                                   unsigned short* __restrict__ latQb,
                                                   unsigned long long* __restrict__ acc) {
    int gid  = blockIdx.x * 256 + threadIdx.x;
    if (gid == 0) { acc[0] = 0ull; acc[1] = 0ull; }
    int lane = gid & 15;
    int row  = gid >> 4;
    if (row >= 2 * BB * CC) return;
    int t  = row >> 14;
    int bc = row & 16383;
    const float* src = (t ? tgt : inp) + (size_t)bc * 64;
    float4 v = reinterpret_cast<const float4*>(src)[lane];
    float s = (v.x + v.y) + (v.z + v.w);
    s += __shfl_xor(s, 1);
    s += __shfl_xor(s, 2);
    s += __shfl_xor(s, 4);
    s += __shfl_xor(s, 8);
    if (lane == 0) {
        int b = bc >> 8, c = bc & 255;
        latQb[(size_t)(t * 64 + b) * CC + c] = (unsigned short)f2bf(s * (1.0f / 64.0f));
    }
}

// ---------------------------------------------------------------------------
// K2: decode GEMM via bf16 MFMA (R15, proven bit-exact).
// ---------------------------------------------------------------------------
__global__ __launch_bounds__(256) void decode_kernel(const unsigned short* __restrict__ latQb,
                                                     const float* __restrict__ muL,
                                                     const float* __restrict__ deltaL,
                                                     const float* __restrict__ muR,
                                                     const float* __restrict__ deltaR,
                                                     const int* __restrict__ labels,
                                                     float* __restrict__ pts3) {
    const int jt   = blockIdx.x;
    const int side = blockIdx.y;
    const int qq   = blockIdx.z;
    const float* __restrict__ delta = side ? deltaR : deltaL;
    const float* __restrict__ mu    = side ? muR : muL;
    const int jb = jt * 64;
    const int q0 = qq * 32;
    const int tid  = threadIdx.x;
    const int w    = tid >> 6;
    const int lane = tid & 63;

    __shared__ unsigned short dB[64 * 264];
    __shared__ unsigned short lB[32 * 264];

#pragma unroll
    for (int i = 0; i < 16; ++i) {
        int idx = i * 256 + tid;
        int row = idx >> 6;
        int ch  = idx & 63;
        int j   = jb + row;
        unsigned u0 = 0, u1 = 0;
        if (j < JD) {
            float4 v = *reinterpret_cast<const float4*>(delta + (size_t)j * CC + ch * 4);
            u0 = f2bf(v.x) | (f2bf(v.y) << 16);
            u1 = f2bf(v.z) | (f2bf(v.w) << 16);
        }
        *reinterpret_cast<uint2*>(&dB[row * 264 + ch * 4]) = make_uint2(u0, u1);
    }
#pragma unroll
    for (int i = 0; i < 4; ++i) {
        int idx = i * 256 + tid;
        int row = idx >> 5;
        int ch  = idx & 31;
        *reinterpret_cast<uint4*>(&lB[row * 264 + ch * 8]) =
            *reinterpret_cast<const uint4*>(latQb + (size_t)(q0 + row) * CC + ch * 8);
    }
    __syncthreads();

    const int col  = lane & 15;
    const int kgrp = lane >> 4;
    bf16x8 bfr[8];
#pragma unroll
    for (int ks = 0; ks < 8; ++ks)
        bfr[ks] = *reinterpret_cast<const bf16x8*>(&dB[(w * 16 + col) * 264 + ks * 32 + kgrp * 8]);

    int j = jb + w * 16 + col;
    float muv = (j < JD) ? mu[j] : 0.f;

#pragma unroll
    for (int mt = 0; mt < 2; ++mt) {
        f32x4 acc = {0.f, 0.f, 0.f, 0.f};
#pragma unroll
        for (int ks = 0; ks < 8; ++ks) {
            bf16x8 a = *reinterpret_cast<const bf16x8*>(&lB[(mt * 16 + col) * 264 + ks * 32 + kgrp * 8]);
            acc = __builtin_amdgcn_mfma_f32_16x16x32_bf16(a, bfr[ks], acc, 0, 0, 0);
        }
        if (j < JD) {
#pragma unroll
            for (int r = 0; r < 4; ++r) {
                int q = q0 + mt * 16 + kgrp * 4 + r;
                if (labels[q & 63] == side)
                    pts3[(size_t)q * JD + j] = acc[r] + muv;
            }
        }
    }
}

// ---------------------------------------------------------------------------
// K2b: pack BOTH encodings per point (R20 slot math, absmax-0 proven):
//  A-enc: [ahx ahx alx ahy ahy aly ahz ahz alz 1 1 a2h a2l 0 0 0]
//  B-enc: [bhx blx bhx bhy bly bhy bhz blz bhz b2h b2l 1 1 0 0 0]
//  dot(A,B) = -2 a.b + |b|^2 + |a|^2 = d^2 (fp32-emulated in fp16 pairs).
//  packA[q] = A-enc(point q);  packB[q^64] = B-enc(point q).
// ---------------------------------------------------------------------------
__global__ __launch_bounds__(256) void pack_kernel(const float* __restrict__ pts3,
                                                   unsigned short* __restrict__ packA,
                                                   unsigned short* __restrict__ packB) {
    int idx = blockIdx.x * 256 + threadIdx.x;   // 128*1536 = 196608 = 768*256
    if (idx >= QQ * NP) return;
    int q = idx / NP;
    int n = idx - q * NP;
    float x = 0.f, y = 0.f, z = 0.f;
    bool real = n < NV;
    if (real) {
        const float* p = pts3 + (size_t)q * JD + n * 3;
        x = p[0]; y = p[1]; z = p[2];
    }
    float p2 = fmaf(x, x, fmaf(y, y, z * z));
    if (!real) p2 = PADV;
    unsigned short p2h = f2h(p2);
    unsigned short p2l = f2h(p2 - h2f(p2h));
    unsigned short one = f2h(1.0f);

    unsigned short ahx = f2h(-2.f * x), ahy = f2h(-2.f * y), ahz = f2h(-2.f * z);
    unsigned short alx = f2h(-2.f * x - h2f(ahx));
    unsigned short aly = f2h(-2.f * y - h2f(ahy));
    unsigned short alz = f2h(-2.f * z - h2f(ahz));
    unsigned short outA[16] = {ahx, ahx, alx, ahy, ahy, aly, ahz, ahz, alz,
                               one, one, p2h, p2l, 0, 0, 0};
    uint4* dA = reinterpret_cast<uint4*>(packA + ((size_t)q * NP + n) * 16);
    dA[0] = *reinterpret_cast<uint4*>(&outA[0]);
    dA[1] = *reinterpret_cast<uint4*>(&outA[8]);

    unsigned short bhx = f2h(x), bhy = f2h(y), bhz = f2h(z);
    unsigned short blx = f2h(x - h2f(bhx));
    unsigned short bly = f2h(y - h2f(bhy));
    unsigned short blz = f2h(z - h2f(bhz));
    unsigned short outB[16] = {bhx, blx, bhx, bhy, bly, bhy, bhz, blz, bhz,
                               p2h, p2l, one, one, 0, 0, 0};
    uint4* dB = reinterpret_cast<uint4*>(packB + ((size_t)(q ^ 64) * NP + n) * 16);
    dB[0] = *reinterpret_cast<uint4*>(&outB[0]);
    dB[1] = *reinterpret_cast<uint4*>(&outB[8]);
}

// ---------------------------------------------------------------------------
// K3: chamfer via 32x32x16 f16 MFMA — stall-free restructure:
//  - NO B-LDS: B-frags straight from L2 (64 lanes read one contiguous 1KB
//    line per tile-col; B per (b,dir) = 49KB, L2-resident). Global frag
//    reads are R20-proven (A-side).
//  - 4 INDEPENDENT waves/block (wave w owns tile-row z*4+w), zero barriers
//    in the main loop; row-min cross-lane reduce once per wave at the end
//    via per-wave LDS transpose slab.
//  - Fits a 64-VGPR self-cap by design (afr4+bf4+d16+rm16+addr ~50) so the
//    compiler's max-occupancy choice causes no spill -> 8 waves/SIMD.
// grid (b 0..63, dir 0..1, z 0..11) = 1536 blocks x 256 thr.
// ---------------------------------------------------------------------------
__global__ __launch_bounds__(256) void chamfer_kernel(const unsigned short* __restrict__ packA,
                                                      const unsigned short* __restrict__ packB,
                                                      unsigned long long* __restrict__ acc,
                                                      float* __restrict__ out) {
    const int b    = blockIdx.x;
    const int dir  = blockIdx.y;
    const int z    = blockIdx.z;
    const int tid  = threadIdx.x;
    const int w    = tid >> 6;
    const int lane = tid & 63;
    const int tr   = z * 4 + w;                  // this wave's tile-row
    const size_t pb = (size_t)(dir * BB + b) * NP;

    __shared__ float slab[4][64][17];            // 17408 B transpose scratch
    __shared__ float wsum[4];

    // A-frag for my tile-row (global, coalesced 1KB per wave)
    f16x8 afr = *reinterpret_cast<const f16x8*>(
        packA + (pb + (size_t)(tr * 32 + (lane & 31))) * 16 + (lane >> 5) * 8);

    // per-lane B base: lane reads point (tc*32 + (lane&31)), k-half (lane>>5)
    const unsigned short* Bp = packB + pb * 16 + (size_t)(lane & 31) * 16 + (lane >> 5) * 8;

    f32x16 zero16;
#pragma unroll
    for (int i = 0; i < 16; ++i) zero16[i] = 0.f;

    float rm[16];
#pragma unroll
    for (int i = 0; i < 16; ++i) rm[i] = 1e30f;

    for (int tc = 0; tc < 48; tc += 2) {         // 48 tile-cols, 2 per iter
        f16x8 bf0 = *reinterpret_cast<const f16x8*>(Bp + (size_t)tc * 512);
        f16x8 bf1 = *reinterpret_cast<const f16x8*>(Bp + (size_t)tc * 512 + 512);
        f32x16 d0 = __builtin_amdgcn_mfma_f32_32x32x16_f16(afr, bf0, zero16, 0, 0, 0);
#pragma unroll
        for (int i = 0; i < 16; ++i) rm[i] = fminf(rm[i], d0[i]);
        f32x16 d1 = __builtin_amdgcn_mfma_f32_32x32x16_f16(afr, bf1, zero16, 0, 0, 0);
#pragma unroll
        for (int i = 0; i < 16; ++i) rm[i] = fminf(rm[i], d1[i]);
    }

    // per-wave row-min transpose-reduce (same-wave LDS write->read, no barrier
    // needed across waves; compiler orders via lgkmcnt — R14-proven pattern)
#pragma unroll
    for (int i = 0; i < 16; ++i) slab[w][lane][i] = rm[i];

    float ssum = 0.f;
    if (lane < 32) {
        int R   = lane;                          // row within tile
        int h   = (R >> 2) & 1;
        int reg = (R & 3) | ((R >> 3) << 2);
        float v = 1e30f;
#pragma unroll
        for (int c = 0; c < 32; ++c)
            v = fminf(v, slab[w][h * 32 + c][reg]);
        int row = tr * 32 + R;
        if (row < NV) ssum = sqrtf(fmaxf(v, 1e-12f));
    }
    ssum += __shfl_xor(ssum, 1);
    ssum += __shfl_xor(ssum, 2);
    ssum += __shfl_xor(ssum, 4);
    ssum += __shfl_xor(ssum, 8);
    ssum += __shfl_xor(ssum, 16);
    ssum += __shfl_xor(ssum, 32);
    if ((tid & 63) == 0) wsum[w] = ssum;
    __syncthreads();
    if (tid == 0) {
        float bs = (wsum[0] + wsum[1]) + (wsum[2] + wsum[3]);
        atomicAdd(acc, (unsigned long long)((double)bs * 16777216.0));
        __threadfence();
        unsigned long long done = atomicAdd(acc + 1, 1ull);
        if (done == 1535) {
            __threadfence();
            unsigned long long total = atomicAdd(acc, 0ull);
            out[0] = (float)((double)total * (0x1p-24 / (64.0 * 1448.0)));
        }
    }
}

extern "C" void kernel_launch(void* const* d_in, const int* in_sizes, int n_in,
                              void* d_out, int out_size, void* d_ws, size_t ws_size,
                              hipStream_t stream) {
    const float* inp    = (const float*)d_in[0];
    const float* tgt    = (const float*)d_in[1];
    const int*   labels = (const int*)d_in[2];
    const float* muL    = (const float*)d_in[3];
    const float* deltaL = (const float*)d_in[4];
    const float* muR    = (const float*)d_in[5];
    const float* deltaR = (const float*)d_in[6];
    float* out = (float*)d_out;

    char* ws = (char*)d_ws;
    unsigned short* latQb = (unsigned short*)ws;                      // 65536 B
    float* pts3           = (float*)(ws + 65536);                     // 2224128 B
    unsigned short* packA = (unsigned short*)(ws + 2289664);          // 128*1536*32 = 6291456 B
    unsigned short* packB = (unsigned short*)(ws + 8581120);          // 6291456 B
    unsigned long long* acc = (unsigned long long*)(ws + 14872576);   // 16 B

    hipLaunchKernelGGL(pool_kernel, dim3(2048), dim3(256), 0, stream, inp, tgt, latQb, acc);
    hipLaunchKernelGGL(decode_kernel, dim3(68, 2, 4), dim3(256), 0, stream,
                       latQb, muL, deltaL, muR, deltaR, labels, pts3);
    hipLaunchKernelGGL(pack_kernel, dim3(768), dim3(256), 0, stream, pts3, packA, packB);
    hipLaunchKernelGGL(chamfer_kernel, dim3(BB, 2, 12), dim3(256), 0, stream,
                       packA, packB, acc, out);
}

// Round 22
// 52.754 us; speedup vs baseline: 1.5435x; 1.5435x over previous
//
#include <hip/hip_runtime.h>

#define NV 1448
#define JD 4344    // 3*NV
#define CC 256
#define BB 64
#define QQ 128     // 2*BB
#define QCOLS 362  // NV/4, columns per chamfer block
#define NROW (2 * BB * NV)  // 185344 row-slots (dir x b x row)

typedef __bf16 bf16x8 __attribute__((ext_vector_type(8)));
typedef float  f32x4  __attribute__((ext_vector_type(4)));

__device__ __forceinline__ unsigned f2bf(float f) {   // fp32 -> bf16 bits, RNE
    unsigned u = __float_as_uint(f);
    return (u + 0x7FFFu + ((u >> 16) & 1u)) >> 16;
}

// ---------------------------------------------------------------------------
// K1: global average pool -> latQb[q][c] (bf16). Thread 0 zeroes acc.
// (R15 version, proven)
// ---------------------------------------------------------------------------
__global__ __launch_bounds__(256) void pool_kernel(const float* __restrict__ inp,
                                                   const float* __restrict__ tgt,
                                                   unsigned short* __restrict__ latQb,
                                                   unsigned long long* __restrict__ acc) {
    int gid  = blockIdx.x * 256 + threadIdx.x;
    if (gid == 0) { acc[0] = 0ull; acc[1] = 0ull; }
    int lane = gid & 15;
    int row  = gid >> 4;
    if (row >= 2 * BB * CC) return;
    int t  = row >> 14;
    int bc = row & 16383;
    const float* src = (t ? tgt : inp) + (size_t)bc * 64;
    float4 v = reinterpret_cast<const float4*>(src)[lane];
    float s = (v.x + v.y) + (v.z + v.w);
    s += __shfl_xor(s, 1);
    s += __shfl_xor(s, 2);
    s += __shfl_xor(s, 4);
    s += __shfl_xor(s, 8);
    if (lane == 0) {
        int b = bc >> 8, c = bc & 255;
        latQb[(size_t)(t * 64 + b) * CC + c] = (unsigned short)f2bf(s * (1.0f / 64.0f));
    }
}

// ---------------------------------------------------------------------------
// K2: decode GEMM via bf16 MFMA 16x16x32 (R15, proven bit-exact, -12us vs
// all fp32 variants). grid (68 jt, 2 side, 4 qq) x 256 thr.
// ---------------------------------------------------------------------------
__global__ __launch_bounds__(256) void decode_kernel(const unsigned short* __restrict__ latQb,
                                                     const float* __restrict__ muL,
                                                     const float* __restrict__ deltaL,
                                                     const float* __restrict__ muR,
                                                     const float* __restrict__ deltaR,
                                                     const int* __restrict__ labels,
                                                     float* __restrict__ pts3) {
    const int jt   = blockIdx.x;
    const int side = blockIdx.y;
    const int qq   = blockIdx.z;
    const float* __restrict__ delta = side ? deltaR : deltaL;
    const float* __restrict__ mu    = side ? muR : muL;
    const int jb = jt * 64;
    const int q0 = qq * 32;
    const int tid  = threadIdx.x;
    const int w    = tid >> 6;
    const int lane = tid & 63;

    __shared__ unsigned short dB[64 * 264];
    __shared__ unsigned short lB[32 * 264];

#pragma unroll
    for (int i = 0; i < 16; ++i) {
        int idx = i * 256 + tid;
        int row = idx >> 6;
        int ch  = idx & 63;
        int j   = jb + row;
        unsigned u0 = 0, u1 = 0;
        if (j < JD) {
            float4 v = *reinterpret_cast<const float4*>(delta + (size_t)j * CC + ch * 4);
            u0 = f2bf(v.x) | (f2bf(v.y) << 16);
            u1 = f2bf(v.z) | (f2bf(v.w) << 16);
        }
        *reinterpret_cast<uint2*>(&dB[row * 264 + ch * 4]) = make_uint2(u0, u1);
    }
#pragma unroll
    for (int i = 0; i < 4; ++i) {
        int idx = i * 256 + tid;
        int row = idx >> 5;
        int ch  = idx & 31;
        *reinterpret_cast<uint4*>(&lB[row * 264 + ch * 8]) =
            *reinterpret_cast<const uint4*>(latQb + (size_t)(q0 + row) * CC + ch * 8);
    }
    __syncthreads();

    const int col  = lane & 15;
    const int kgrp = lane >> 4;
    bf16x8 bfr[8];
#pragma unroll
    for (int ks = 0; ks < 8; ++ks)
        bfr[ks] = *reinterpret_cast<const bf16x8*>(&dB[(w * 16 + col) * 264 + ks * 32 + kgrp * 8]);

    int j = jb + w * 16 + col;
    float muv = (j < JD) ? mu[j] : 0.f;

#pragma unroll
    for (int mt = 0; mt < 2; ++mt) {
        f32x4 acc = {0.f, 0.f, 0.f, 0.f};
#pragma unroll
        for (int ks = 0; ks < 8; ++ks) {
            bf16x8 a = *reinterpret_cast<const bf16x8*>(&lB[(mt * 16 + col) * 264 + ks * 32 + kgrp * 8]);
            acc = __builtin_amdgcn_mfma_f32_16x16x32_bf16(a, bfr[ks], acc, 0, 0, 0);
        }
        if (j < JD) {
#pragma unroll
            for (int r = 0; r < 4; ++r) {
                int q = q0 + mt * 16 + kgrp * 4 + r;
                if (labels[q & 63] == side)
                    pts3[(size_t)q * JD + j] = acc[r] + muv;
            }
        }
    }
}

// ---------------------------------------------------------------------------
// K3: fp32 chamfer, pack fused, forced v_min3_f32 (R11, proven ~27us;
// ~50% of its 3.5-instr/pair VALU roofline — best of 14 variants tried).
// grid (chunk 0..2, b 0..63, z 0..7: dir=z>>2, q=z&3); 1536 blocks = 6/CU.
// ---------------------------------------------------------------------------
__global__ __launch_bounds__(256) void chamfer_kernel(const float* __restrict__ pts3,
                                                      float* __restrict__ pmin) {
    const int chunk = blockIdx.x;
    const int b     = blockIdx.y;
    const int dir   = blockIdx.z >> 2;
    const int q     = blockIdx.z & 3;
    const int qa = dir * BB + b;
    const int qb = (1 - dir) * BB + b;
    const float* __restrict__ A3 = pts3 + (size_t)qa * JD;
    const float* __restrict__ B3 = pts3 + (size_t)qb * JD + q * (QCOLS * 3);

    __shared__ float4 Bs[QCOLS];
    const int tid = threadIdx.x;
    for (int i = tid; i < QCOLS; i += 256) {
        float x = B3[3 * i], y = B3[3 * i + 1], z = B3[3 * i + 2];
        Bs[i] = make_float4(-2.f * x, -2.f * y, -2.f * z, fmaf(x, x, fmaf(y, y, z * z)));
    }
    __syncthreads();

    int r0 = chunk * 512 + tid;
    int r1 = r0 + 256;
    float a0x = 0.f, a0y = 0.f, a0z = 0.f, a0w = 0.f;
    float a1x = 0.f, a1y = 0.f, a1z = 0.f, a1w = 0.f;
    if (r0 < NV) {
        a0x = A3[3 * r0]; a0y = A3[3 * r0 + 1]; a0z = A3[3 * r0 + 2];
        a0w = fmaf(a0x, a0x, fmaf(a0y, a0y, a0z * a0z));
    }
    if (r1 < NV) {
        a1x = A3[3 * r1]; a1y = A3[3 * r1 + 1]; a1z = A3[3 * r1 + 2];
        a1w = fmaf(a1x, a1x, fmaf(a1y, a1y, a1z * a1z));
    }
    float m0 = 1e30f, m1 = 1e30f;

#pragma unroll 2
    for (int m = 0; m < QCOLS; m += 2) {
        float4 b0 = Bs[m];
        float4 b1 = Bs[m + 1];
        float d00 = fmaf(b0.x, a0x, fmaf(b0.y, a0y, fmaf(b0.z, a0z, b0.w)));
        float d01 = fmaf(b1.x, a0x, fmaf(b1.y, a0y, fmaf(b1.z, a0z, b1.w)));
        asm("v_min3_f32 %0, %0, %1, %2" : "+v"(m0) : "v"(d00), "v"(d01));
        float d10 = fmaf(b0.x, a1x, fmaf(b0.y, a1y, fmaf(b0.z, a1z, b0.w)));
        float d11 = fmaf(b1.x, a1x, fmaf(b1.y, a1y, fmaf(b1.z, a1z, b1.w)));
        asm("v_min3_f32 %0, %0, %1, %2" : "+v"(m1) : "v"(d10), "v"(d11));
    }

    size_t base = (size_t)q * NROW + (size_t)qa * NV;
    if (r0 < NV) pmin[base + r0] = m0 + a0w;
    if (r1 < NV) pmin[base + r1] = m1 + a1w;
}

// ---------------------------------------------------------------------------
// K4: combine 4 quarter-mins, sqrt, block sums -> fixed-point atomic;
// last block writes out. 256 blocks x 724 rows exact. (R11, proven)
// ---------------------------------------------------------------------------
__global__ __launch_bounds__(256) void combine_kernel(const float* __restrict__ pmin,
                                                      unsigned long long* __restrict__ acc,
                                                      float* __restrict__ out) {
    const int base = blockIdx.x * 724;
    const int tid  = threadIdx.x;
    float s = 0.f;
#pragma unroll
    for (int it = 0; it < 3; ++it) {
        int idx = it * 256 + tid;
        if (idx < 724) {
            int g = base + idx;
            float v = fminf(fminf(pmin[g], pmin[g + NROW]),
                            fminf(pmin[g + 2 * NROW], pmin[g + 3 * NROW]));
            s += sqrtf(fmaxf(v, 1e-12f));
        }
    }
    s += __shfl_xor(s, 1);
    s += __shfl_xor(s, 2);
    s += __shfl_xor(s, 4);
    s += __shfl_xor(s, 8);
    s += __shfl_xor(s, 16);
    s += __shfl_xor(s, 32);
    __shared__ float wsum[4];
    if ((tid & 63) == 0) wsum[tid >> 6] = s;
    __syncthreads();
    if (tid == 0) {
        float bs = wsum[0] + wsum[1] + wsum[2] + wsum[3];
        unsigned long long qv = (unsigned long long)((double)bs * 16777216.0); // 2^24 fixed pt
        atomicAdd(acc, qv);
        __threadfence();
        unsigned long long done = atomicAdd(acc + 1, 1ull);
        if (done == 255) {
            __threadfence();
            unsigned long long total = atomicAdd(acc, 0ull);
            out[0] = (float)((double)total * (0x1p-24 / (64.0 * 1448.0)));
        }
    }
}

extern "C" void kernel_launch(void* const* d_in, const int* in_sizes, int n_in,
                              void* d_out, int out_size, void* d_ws, size_t ws_size,
                              hipStream_t stream) {
    const float* inp    = (const float*)d_in[0];
    const float* tgt    = (const float*)d_in[1];
    const int*   labels = (const int*)d_in[2];
    const float* muL    = (const float*)d_in[3];
    const float* deltaL = (const float*)d_in[4];
    const float* muR    = (const float*)d_in[5];
    const float* deltaR = (const float*)d_in[6];
    float* out = (float*)d_out;

    char* ws = (char*)d_ws;
    unsigned short* latQb = (unsigned short*)ws;                 // 128*256*2 = 65536 B
    float* pts3 = (float*)(ws + 65536);                          // 128*4344*4 = 2224128 B
    float* pmin = (float*)(ws + 65536 + 2224128);                // 4*185344*4 = 2965504 B
    unsigned long long* acc = (unsigned long long*)(ws + 65536 + 2224128 + 2965504);

    hipLaunchKernelGGL(pool_kernel, dim3(2048), dim3(256), 0, stream, inp, tgt, latQb, acc);
    hipLaunchKernelGGL(decode_kernel, dim3(68, 2, 4), dim3(256), 0, stream,
                       latQb, muL, deltaL, muR, deltaR, labels, pts3);
    hipLaunchKernelGGL(chamfer_kernel, dim3(3, 64, 8), dim3(256), 0, stream,
                       pts3, pmin);
    hipLaunchKernelGGL(combine_kernel, dim3(256), dim3(256), 0, stream, pmin, acc, out);
}

// Round 23
// 52.517 us; speedup vs baseline: 1.5504x; 1.0045x over previous
//
#include <hip/hip_runtime.h>

#define NV 1448
#define JD 4344    // 3*NV
#define CC 256
#define BB 64
#define QQ 128     // 2*BB
#define QCOLS 362  // NV/4, columns per chamfer block
#define NROW (2 * BB * NV)  // 185344 row-slots (dir x b x row)
#define RPT 6      // rows per thread (256*6 = 1536 >= 1448, single chunk)

typedef __bf16 bf16x8 __attribute__((ext_vector_type(8)));
typedef float  f32x4  __attribute__((ext_vector_type(4)));

__device__ __forceinline__ unsigned f2bf(float f) {   // fp32 -> bf16 bits, RNE
    unsigned u = __float_as_uint(f);
    return (u + 0x7FFFu + ((u >> 16) & 1u)) >> 16;
}

// ---------------------------------------------------------------------------
// K1: global average pool -> latQb[q][c] (bf16). Thread 0 zeroes acc.
// ---------------------------------------------------------------------------
__global__ __launch_bounds__(256) void pool_kernel(const float* __restrict__ inp,
                                                   const float* __restrict__ tgt,
                                                   unsigned short* __restrict__ latQb,
                                                   unsigned long long* __restrict__ acc) {
    int gid  = blockIdx.x * 256 + threadIdx.x;
    if (gid == 0) { acc[0] = 0ull; acc[1] = 0ull; }
    int lane = gid & 15;
    int row  = gid >> 4;
    if (row >= 2 * BB * CC) return;
    int t  = row >> 14;
    int bc = row & 16383;
    const float* src = (t ? tgt : inp) + (size_t)bc * 64;
    float4 v = reinterpret_cast<const float4*>(src)[lane];
    float s = (v.x + v.y) + (v.z + v.w);
    s += __shfl_xor(s, 1);
    s += __shfl_xor(s, 2);
    s += __shfl_xor(s, 4);
    s += __shfl_xor(s, 8);
    if (lane == 0) {
        int b = bc >> 8, c = bc & 255;
        latQb[(size_t)(t * 64 + b) * CC + c] = (unsigned short)f2bf(s * (1.0f / 64.0f));
    }
}

// ---------------------------------------------------------------------------
// K2: decode GEMM via bf16 MFMA 16x16x32 (R15, proven bit-exact).
// ---------------------------------------------------------------------------
__global__ __launch_bounds__(256) void decode_kernel(const unsigned short* __restrict__ latQb,
                                                     const float* __restrict__ muL,
                                                     const float* __restrict__ deltaL,
                                                     const float* __restrict__ muR,
                                                     const float* __restrict__ deltaR,
                                                     const int* __restrict__ labels,
                                                     float* __restrict__ pts3) {
    const int jt   = blockIdx.x;
    const int side = blockIdx.y;
    const int qq   = blockIdx.z;
    const float* __restrict__ delta = side ? deltaR : deltaL;
    const float* __restrict__ mu    = side ? muR : muL;
    const int jb = jt * 64;
    const int q0 = qq * 32;
    const int tid  = threadIdx.x;
    const int w    = tid >> 6;
    const int lane = tid & 63;

    __shared__ unsigned short dB[64 * 264];
    __shared__ unsigned short lB[32 * 264];

#pragma unroll
    for (int i = 0; i < 16; ++i) {
        int idx = i * 256 + tid;
        int row = idx >> 6;
        int ch  = idx & 63;
        int j   = jb + row;
        unsigned u0 = 0, u1 = 0;
        if (j < JD) {
            float4 v = *reinterpret_cast<const float4*>(delta + (size_t)j * CC + ch * 4);
            u0 = f2bf(v.x) | (f2bf(v.y) << 16);
            u1 = f2bf(v.z) | (f2bf(v.w) << 16);
        }
        *reinterpret_cast<uint2*>(&dB[row * 264 + ch * 4]) = make_uint2(u0, u1);
    }
#pragma unroll
    for (int i = 0; i < 4; ++i) {
        int idx = i * 256 + tid;
        int row = idx >> 5;
        int ch  = idx & 31;
        *reinterpret_cast<uint4*>(&lB[row * 264 + ch * 8]) =
            *reinterpret_cast<const uint4*>(latQb + (size_t)(q0 + row) * CC + ch * 8);
    }
    __syncthreads();

    const int col  = lane & 15;
    const int kgrp = lane >> 4;
    bf16x8 bfr[8];
#pragma unroll
    for (int ks = 0; ks < 8; ++ks)
        bfr[ks] = *reinterpret_cast<const bf16x8*>(&dB[(w * 16 + col) * 264 + ks * 32 + kgrp * 8]);

    int j = jb + w * 16 + col;
    float muv = (j < JD) ? mu[j] : 0.f;

#pragma unroll
    for (int mt = 0; mt < 2; ++mt) {
        f32x4 acc = {0.f, 0.f, 0.f, 0.f};
#pragma unroll
        for (int ks = 0; ks < 8; ++ks) {
            bf16x8 a = *reinterpret_cast<const bf16x8*>(&lB[(mt * 16 + col) * 264 + ks * 32 + kgrp * 8]);
            acc = __builtin_amdgcn_mfma_f32_16x16x32_bf16(a, bfr[ks], acc, 0, 0, 0);
        }
        if (j < JD) {
#pragma unroll
            for (int r = 0; r < 4; ++r) {
                int q = q0 + mt * 16 + kgrp * 4 + r;
                if (labels[q & 63] == side)
                    pts3[(size_t)q * JD + j] = acc[r] + muv;
            }
        }
    }
}

// ---------------------------------------------------------------------------
// K3: fp32 chamfer, RPT=6 rows/thread — one ds_read_b128 broadcast now feeds
// 6 rows instead of 2. LDS-pipe instrs /3 (2.2M -> 741K wave-instrs: the
// measured 27us matched the LDS model at ~8cyc/broadcast; VALU issue floor
// is ~13us). min3 forced (R9-proven). Pack fused (reads pts3).
// grid (b 0..63, z 0..7: dir=z>>2, q=z&3) = 512 blocks x 256 thr.
// All per-row arrays statically unrolled (rule #20).
// ---------------------------------------------------------------------------
__global__ __launch_bounds__(256) void chamfer_kernel(const float* __restrict__ pts3,
                                                      float* __restrict__ pmin) {
    const int b   = blockIdx.x;
    const int dir = blockIdx.y >> 2;
    const int q   = blockIdx.y & 3;
    const int qa = dir * BB + b;
    const int qb = (1 - dir) * BB + b;
    const float* __restrict__ A3 = pts3 + (size_t)qa * JD;
    const float* __restrict__ B3 = pts3 + (size_t)qb * JD + q * (QCOLS * 3);

    __shared__ float4 Bs[QCOLS];
    const int tid = threadIdx.x;
    for (int i = tid; i < QCOLS; i += 256) {
        float x = B3[3 * i], y = B3[3 * i + 1], z = B3[3 * i + 2];
        Bs[i] = make_float4(-2.f * x, -2.f * y, -2.f * z, fmaf(x, x, fmaf(y, y, z * z)));
    }
    __syncthreads();

    float ax[RPT], ay[RPT], az[RPT], aw[RPT], mn[RPT];
#pragma unroll
    for (int k = 0; k < RPT; ++k) {
        int r = tid + 256 * k;
        bool v = r < NV;
        float x = v ? A3[3 * r]     : 0.f;
        float y = v ? A3[3 * r + 1] : 0.f;
        float z = v ? A3[3 * r + 2] : 0.f;
        ax[k] = x; ay[k] = y; az[k] = z;
        aw[k] = fmaf(x, x, fmaf(y, y, z * z));
        mn[k] = 1e30f;
    }

    for (int m = 0; m < QCOLS; m += 2) {        // 362 even: no tail
        float4 b0 = Bs[m];
        float4 b1 = Bs[m + 1];
#pragma unroll
        for (int k = 0; k < RPT; ++k) {
            float d0 = fmaf(b0.x, ax[k], fmaf(b0.y, ay[k], fmaf(b0.z, az[k], b0.w)));
            float d1 = fmaf(b1.x, ax[k], fmaf(b1.y, ay[k], fmaf(b1.z, az[k], b1.w)));
            asm("v_min3_f32 %0, %0, %1, %2" : "+v"(mn[k]) : "v"(d0), "v"(d1));
        }
    }

    float* dst = pmin + (size_t)q * NROW + (size_t)qa * NV;
#pragma unroll
    for (int k = 0; k < RPT; ++k) {
        int r = tid + 256 * k;
        if (r < NV) dst[r] = mn[k] + aw[k];
    }
}

// ---------------------------------------------------------------------------
// K4: combine 4 quarter-mins, sqrt, block sums -> fixed-point atomic;
// last block writes out. 256 blocks x 724 rows exact. (R11/R22, proven)
// ---------------------------------------------------------------------------
__global__ __launch_bounds__(256) void combine_kernel(const float* __restrict__ pmin,
                                                      unsigned long long* __restrict__ acc,
                                                      float* __restrict__ out) {
    const int base = blockIdx.x * 724;
    const int tid  = threadIdx.x;
    float s = 0.f;
#pragma unroll
    for (int it = 0; it < 3; ++it) {
        int idx = it * 256 + tid;
        if (idx < 724) {
            int g = base + idx;
            float v = fminf(fminf(pmin[g], pmin[g + NROW]),
                            fminf(pmin[g + 2 * NROW], pmin[g + 3 * NROW]));
            s += sqrtf(fmaxf(v, 1e-12f));
        }
    }
    s += __shfl_xor(s, 1);
    s += __shfl_xor(s, 2);
    s += __shfl_xor(s, 4);
    s += __shfl_xor(s, 8);
    s += __shfl_xor(s, 16);
    s += __shfl_xor(s, 32);
    __shared__ float wsum[4];
    if ((tid & 63) == 0) wsum[tid >> 6] = s;
    __syncthreads();
    if (tid == 0) {
        float bs = wsum[0] + wsum[1] + wsum[2] + wsum[3];
        unsigned long long qv = (unsigned long long)((double)bs * 16777216.0); // 2^24 fixed pt
        atomicAdd(acc, qv);
        __threadfence();
        unsigned long long done = atomicAdd(acc + 1, 1ull);
        if (done == 255) {
            __threadfence();
            unsigned long long total = atomicAdd(acc, 0ull);
            out[0] = (float)((double)total * (0x1p-24 / (64.0 * 1448.0)));
        }
    }
}

extern "C" void kernel_launch(void* const* d_in, const int* in_sizes, int n_in,
                              void* d_out, int out_size, void* d_ws, size_t ws_size,
                              hipStream_t stream) {
    const float* inp    = (const float*)d_in[0];
    const float* tgt    = (const float*)d_in[1];
    const int*   labels = (const int*)d_in[2];
    const float* muL    = (const float*)d_in[3];
    const float* deltaL = (const float*)d_in[4];
    const float* muR    = (const float*)d_in[5];
    const float* deltaR = (const float*)d_in[6];
    float* out = (float*)d_out;

    char* ws = (char*)d_ws;
    unsigned short* latQb = (unsigned short*)ws;                 // 128*256*2 = 65536 B
    float* pts3 = (float*)(ws + 65536);                          // 128*4344*4 = 2224128 B
    float* pmin = (float*)(ws + 65536 + 2224128);                // 4*185344*4 = 2965504 B
    unsigned long long* acc = (unsigned long long*)(ws + 65536 + 2224128 + 2965504);

    hipLaunchKernelGGL(pool_kernel, dim3(2048), dim3(256), 0, stream, inp, tgt, latQb, acc);
    hipLaunchKernelGGL(decode_kernel, dim3(68, 2, 4), dim3(256), 0, stream,
                       latQb, muL, deltaL, muR, deltaR, labels, pts3);
    hipLaunchKernelGGL(chamfer_kernel, dim3(64, 8), dim3(256), 0, stream,
                       pts3, pmin);
    hipLaunchKernelGGL(combine_kernel, dim3(256), dim3(256), 0, stream, pmin, acc, out);
}